// Round 1
// baseline (451.863 us; speedup 1.0000x reference)
//
#include <hip/hip_runtime.h>
#include <math.h>

#define CC 2048   // channels (C)
#define DD 256    // reduced channels (D)
#define PP 4096   // HW = 64*64
#define NB 4      // batch

typedef float f32x4 __attribute__((ext_vector_type(4)));
typedef __bf16 bfrag __attribute__((ext_vector_type(8)));

#define AS1(p) ((const __attribute__((address_space(1))) void*)(p))
#define AS3(p) ((__attribute__((address_space(3))) void*)(p))

__device__ __forceinline__ unsigned short f2bf(float f) {
    unsigned int u = __float_as_uint(f);
    u = (u + 0x7fffu + ((u >> 16) & 1u)) >> 16;
    return (unsigned short)u;
}

// ---------------- w3 fp32 -> bf16 ----------------
__global__ void cvt_w3(const float* __restrict__ w, unsigned short* __restrict__ o) {
    int i = (blockIdx.x * 256 + threadIdx.x) * 4;   // 4096 blocks * 256 thr * 4 = 4M elems
    float4 v = *(const float4*)(w + i);
    ushort4 r;
    r.x = f2bf(v.x); r.y = f2bf(v.y); r.z = f2bf(v.z); r.w = f2bf(v.w);
    *(ushort4*)(o + i) = r;
}

// ---------------- x [n][c][p] fp32 -> xT [n][p][c] bf16 ----------------
__global__ void transpose_cvt(const float* __restrict__ x, unsigned short* __restrict__ xT) {
    __shared__ float tile[32][33];
    const int n  = blockIdx.z;
    const int c0 = blockIdx.y * 32;
    const int p0 = blockIdx.x * 32;
    const int tx = threadIdx.x;   // 0..31
    const int ty = threadIdx.y;   // 0..7
    const float* xn = x + (size_t)n * CC * PP;
#pragma unroll
    for (int j = 0; j < 4; ++j) {
        int c = c0 + ty + j * 8;
        tile[ty + j * 8][tx] = xn[(size_t)c * PP + p0 + tx];
    }
    __syncthreads();
    unsigned short* xTn = xT + (size_t)n * PP * CC;
#pragma unroll
    for (int j = 0; j < 4; ++j) {
        int p = p0 + ty + j * 8;
        xTn[(size_t)p * CC + c0 + tx] = f2bf(tile[tx][ty + j * 8]);
    }
}

// ---------------- assembly = relu(w3 . x + b3)  (m97-style MFMA GEMM) ----------------
// A = w3b [2048][2048] bf16 (row-major, K-contiguous)
// B = xT  [nb][4096][2048] bf16 (p-major, K-contiguous)  -> C[o][p]
__global__ __launch_bounds__(256) void gemm_assembly(
    const unsigned short* __restrict__ w3b,
    const unsigned short* __restrict__ xT,
    const float* __restrict__ b3,
    float* __restrict__ out)
{
    __shared__ unsigned short smA[128 * 32];  // [row m][k] 8KB
    __shared__ unsigned short smB[128 * 32];  // [row p][k] 8KB

    const int t    = threadIdx.x;
    const int wave = t >> 6;
    const int lane = t & 63;
    const int quad = lane >> 4;
    const int l16  = lane & 15;
    const int m0 = blockIdx.y * 128;
    const int p0 = blockIdx.x * 128;
    const int nb = blockIdx.z;

    // staging: thread t loads 16B = 8 bf16: row = chunk*64 + t/4, col8 = (t&3)*8
    const unsigned short* Ag = w3b + (size_t)(m0 + (t >> 2)) * CC + ((t & 3) * 8);
    const unsigned short* Bg = xT + (size_t)nb * PP * CC + (size_t)(p0 + (t >> 2)) * CC + ((t & 3) * 8);
    char* ldsA = (char*)smA + wave * 1024;   // wave-uniform base; HW adds lane*16
    char* ldsB = (char*)smB + wave * 1024;

    f32x4 acc[4][4];
#pragma unroll
    for (int mi = 0; mi < 4; ++mi)
#pragma unroll
        for (int ni = 0; ni < 4; ++ni)
            acc[mi][ni] = (f32x4){0.f, 0.f, 0.f, 0.f};

    const int wr = (wave >> 1) * 64;   // wave row offset in 128-tile
    const int wc = (wave & 1) * 64;    // wave col offset

    for (int kt = 0; kt < CC; kt += 32) {
        __builtin_amdgcn_global_load_lds(AS1(Ag + kt),            AS3(ldsA),        16, 0, 0);
        __builtin_amdgcn_global_load_lds(AS1(Ag + 64 * CC + kt),  AS3(ldsA + 4096), 16, 0, 0);
        __builtin_amdgcn_global_load_lds(AS1(Bg + kt),            AS3(ldsB),        16, 0, 0);
        __builtin_amdgcn_global_load_lds(AS1(Bg + 64 * CC + kt),  AS3(ldsB + 4096), 16, 0, 0);
        __syncthreads();

        bfrag af[4], bfv[4];
#pragma unroll
        for (int mi = 0; mi < 4; ++mi)
            af[mi] = *(const bfrag*)((const char*)smA + (wr + mi * 16 + l16) * 64 + quad * 16);
#pragma unroll
        for (int ni = 0; ni < 4; ++ni)
            bfv[ni] = *(const bfrag*)((const char*)smB + (wc + ni * 16 + l16) * 64 + quad * 16);
#pragma unroll
        for (int mi = 0; mi < 4; ++mi)
#pragma unroll
            for (int ni = 0; ni < 4; ++ni)
                acc[mi][ni] = __builtin_amdgcn_mfma_f32_16x16x32_bf16(af[mi], bfv[ni], acc[mi][ni], 0, 0, 0);
        __syncthreads();
    }

    // epilogue: bias + relu; D layout: row = quad*4 + reg, col = l16
    float* outn = out + (size_t)nb * CC * PP;
#pragma unroll
    for (int mi = 0; mi < 4; ++mi) {
        const int ob = m0 + wr + mi * 16 + quad * 4;
#pragma unroll
        for (int r = 0; r < 4; ++r) {
            const float bias = b3[ob + r];
            float* orow = outn + (size_t)(ob + r) * PP + p0 + wc + l16;
#pragma unroll
            for (int ni = 0; ni < 4; ++ni) {
                float v = acc[mi][ni][r] + bias;
                orow[ni * 16] = v > 0.f ? v : 0.f;
            }
        }
    }
}

// ---------------- guarded attention fallback (alpha != 0 only; alpha==0 in this bench) ----
__global__ void fb_e12(const float* __restrict__ x,
                       const float* __restrict__ w1, const float* __restrict__ b1,
                       const float* __restrict__ w2, const float* __restrict__ b2,
                       const float* __restrict__ alpha,
                       float* __restrict__ e1, float* __restrict__ e2) {
    if (alpha[0] == 0.f) return;
    const size_t total = (size_t)NB * DD * PP;
    for (size_t idx = (size_t)blockIdx.x * blockDim.x + threadIdx.x; idx < total;
         idx += (size_t)gridDim.x * blockDim.x) {
        int p = (int)(idx % PP);
        size_t nd = idx / PP;
        int d = (int)(nd % DD);
        int n = (int)(nd / DD);
        const float* xn = x + (size_t)n * CC * PP + p;
        float s1 = b1[d], s2 = b2[d];
        for (int c = 0; c < CC; ++c) {
            float xv = xn[(size_t)c * PP];
            s1 += w1[(size_t)d * CC + c] * xv;
            s2 += w2[(size_t)d * CC + c] * xv;
        }
        e1[idx] = fmaxf(s1, 0.f);
        e2[idx] = fmaxf(s2, 0.f);
    }
}

__global__ void fb_attn(const float* __restrict__ x,
                        const float* __restrict__ e1, const float* __restrict__ e2,
                        const float* __restrict__ alpha,
                        float* __restrict__ out) {
    const float a = alpha[0];
    if (a == 0.f) return;
    __shared__ float s[PP];
    __shared__ float e1i[DD];
    __shared__ float red[256];
    const int n = blockIdx.y, i = blockIdx.x, t = threadIdx.x;
    const float* e1n = e1 + (size_t)n * DD * PP;
    const float* e2n = e2 + (size_t)n * DD * PP;
    e1i[t] = (t < DD) ? e1n[(size_t)t * PP + i] : 0.f;
    __syncthreads();
    for (int j = t; j < PP; j += 256) {
        float acc = 0.f;
        for (int d = 0; d < DD; ++d) acc += e1i[d] * e2n[(size_t)d * PP + j];
        s[j] = acc;
    }
    __syncthreads();
    float m = -INFINITY;
    for (int j = t; j < PP; j += 256) m = fmaxf(m, s[j]);
    red[t] = m; __syncthreads();
    for (int o = 128; o > 0; o >>= 1) { if (t < o) red[t] = fmaxf(red[t], red[t + o]); __syncthreads(); }
    m = red[0]; __syncthreads();
    float l = 0.f;
    for (int j = t; j < PP; j += 256) { float e = __expf(s[j] - m); s[j] = e; l += e; }
    red[t] = l; __syncthreads();
    for (int o = 128; o > 0; o >>= 1) { if (t < o) red[t] += red[t + o]; __syncthreads(); }
    l = red[0]; __syncthreads();
    const float inv = a / l;
    const float* xn = x + (size_t)n * CC * PP;
    float* on = out + (size_t)n * CC * PP;
    for (int c = t; c < CC; c += 256) {
        const float* xr = xn + (size_t)c * PP;
        float acc = 0.f;
        for (int j = 0; j < PP; ++j) acc += s[j] * xr[j];
        on[(size_t)c * PP + i] += inv * acc;
    }
}

extern "C" void kernel_launch(void* const* d_in, const int* in_sizes, int n_in,
                              void* d_out, int out_size, void* d_ws, size_t ws_size,
                              hipStream_t stream) {
    (void)in_sizes; (void)n_in; (void)out_size; (void)ws_size;
    const float* x     = (const float*)d_in[0];
    const float* w1    = (const float*)d_in[1];
    const float* b1    = (const float*)d_in[2];
    const float* w2    = (const float*)d_in[3];
    const float* b2    = (const float*)d_in[4];
    const float* w3    = (const float*)d_in[5];
    const float* b3    = (const float*)d_in[6];
    const float* alpha = (const float*)d_in[7];
    float* out = (float*)d_out;

    // ws layout: [0, 64MB) xT bf16 ; [64MB, 72MB) w3b bf16 ; fallback e1/e2 reuse [0, 32MB)
    unsigned short* xT  = (unsigned short*)d_ws;
    unsigned short* w3b = (unsigned short*)((char*)d_ws + (size_t)NB * PP * CC * 2);
    float* e1 = (float*)d_ws;                       // reused after gemm consumes xT
    float* e2 = e1 + (size_t)NB * DD * PP;

    cvt_w3<<<dim3(4096), dim3(256), 0, stream>>>(w3, w3b);
    transpose_cvt<<<dim3(PP / 32, CC / 32, NB), dim3(32, 8), 0, stream>>>(x, xT);
    gemm_assembly<<<dim3(PP / 128, CC / 128, NB), dim3(256), 0, stream>>>(w3b, xT, b3, out);
    // attention path: no-ops when alpha == 0 (true for this input set)
    fb_e12<<<dim3(4096), dim3(256), 0, stream>>>(x, w1, b1, w2, b2, alpha, e1, e2);
    fb_attn<<<dim3(PP, NB), dim3(256), 0, stream>>>(x, e1, e2, alpha, out);
}

// Round 2
// 389.694 us; speedup vs baseline: 1.1595x; 1.1595x over previous
//
#include <hip/hip_runtime.h>
#include <math.h>

#define CC 2048   // channels (C)
#define DD 256    // reduced channels (D)
#define PP 4096   // HW = 64*64
#define NB 4      // batch

typedef float f32x16 __attribute__((ext_vector_type(16)));
typedef __bf16 bfrag __attribute__((ext_vector_type(8)));

#define AS1(p) ((const __attribute__((address_space(1))) void*)(p))
#define AS3(p) ((__attribute__((address_space(3))) void*)(p))

__device__ __forceinline__ unsigned short f2bf(float f) {
    unsigned int u = __float_as_uint(f);
    u = (u + 0x7fffu + ((u >> 16) & 1u)) >> 16;
    return (unsigned short)u;
}

// ---------------- w3 fp32 -> bf16 (16 MB read, 8 MB write) ----------------
__global__ __launch_bounds__(256) void cvt_w3(const float* __restrict__ w, unsigned short* __restrict__ o) {
    int base = (blockIdx.x * 256 + threadIdx.x) * 16;   // 1024 blocks * 256 thr * 16 = 4M
#pragma unroll
    for (int j = 0; j < 4; ++j) {
        float4 v = *(const float4*)(w + base + j * 4);
        ushort4 r;
        r.x = f2bf(v.x); r.y = f2bf(v.y); r.z = f2bf(v.z); r.w = f2bf(v.w);
        *(ushort4*)(o + base + j * 4) = r;
    }
}

// ---------------- x [n][c][p] fp32 -> xT [n][p][c] bf16 ----------------
// 64x64 tile per 256-thread block; fp32 LDS tile (row stride 68 words);
// writes are ushort4 -> 128B contiguous per 16 lanes.
__global__ __launch_bounds__(256) void transpose_cvt(const float* __restrict__ x, unsigned short* __restrict__ xT) {
    __shared__ float tile[64 * 68];
    const int n  = blockIdx.z;
    const int c0 = blockIdx.y * 64;
    const int p0 = blockIdx.x * 64;
    const int t  = threadIdx.x;
    const float* xn = x + (size_t)n * CC * PP;
    {
        const int cl = t >> 4;          // 0..15
        const int pl = (t & 15) * 4;    // 0..60
#pragma unroll
        for (int ps = 0; ps < 4; ++ps) {
            int c = cl + ps * 16;
            float4 v = *(const float4*)(xn + (size_t)(c0 + c) * PP + p0 + pl);
            *(float4*)(tile + c * 68 + pl) = v;
        }
    }
    __syncthreads();
    unsigned short* xTn = xT + (size_t)n * PP * CC;
    {
        const int pl2 = t >> 4;         // 0..15
        const int c4  = (t & 15) * 4;   // 0..60
#pragma unroll
        for (int ps = 0; ps < 4; ++ps) {
            int p = pl2 + ps * 16;
            ushort4 r;
            r.x = f2bf(tile[(c4 + 0) * 68 + p]);
            r.y = f2bf(tile[(c4 + 1) * 68 + p]);
            r.z = f2bf(tile[(c4 + 2) * 68 + p]);
            r.w = f2bf(tile[(c4 + 3) * 68 + p]);
            *(ushort4*)(xTn + (size_t)(p0 + p) * CC + c0 + c4) = r;
        }
    }
}

// ---------------- assembly = relu(w3 . x + b3) ----------------
// 128x128 tile, BK=64, 4 waves each 64x64 via 2x2 of mfma_f32_32x32x16_bf16.
// LDS rows are 128B (64 bf16); chunk slot s of row r holds global chunk s^(r&7)
// (XOR swizzle applied on the GLOBAL lane address so global_load_lds's
// wave-uniform-base + lane*16 layout is preserved).
__global__ __launch_bounds__(256, 4) void gemm_assembly(
    const unsigned short* __restrict__ w3b,
    const unsigned short* __restrict__ xT,
    const float* __restrict__ b3,
    float* __restrict__ out)
{
    __shared__ __align__(16) unsigned short smA[128 * 64];  // 16KB
    __shared__ __align__(16) unsigned short smB[128 * 64];  // 16KB

    const int t    = threadIdx.x;
    const int wave = t >> 6;
    const int lane = t & 63;
    const int l31  = lane & 31;
    const int lh   = lane >> 5;     // k-half for A/B fragments
    const int swz  = lane & 7;
    const int m0 = blockIdx.y * 128;
    const int p0 = blockIdx.x * 128;
    const int nb = blockIdx.z;

    // staging: thread t covers row rA = t>>3 (+j*32), fetches global chunk g
    const int rA = t >> 3;
    const int g  = (t & 7) ^ ((t >> 3) & 7);
    const unsigned short* Ag = w3b + (size_t)(m0 + rA) * CC + g * 8;
    const unsigned short* Bg = xT + (size_t)nb * PP * CC + (size_t)(p0 + rA) * CC + g * 8;
    char* ldsA = (char*)smA + wave * 1024;   // + j*4096 per call; HW adds lane*16
    char* ldsB = (char*)smB + wave * 1024;

    const int wr = (wave >> 1) * 64;   // wave row offset
    const int wc = (wave & 1) * 64;    // wave col offset

    f32x16 acc00 = {}, acc01 = {}, acc10 = {}, acc11 = {};

    const char* pA0 = (const char*)smA + (wr + l31) * 128;
    const char* pA1 = (const char*)smA + (wr + 32 + l31) * 128;
    const char* pB0 = (const char*)smB + (wc + l31) * 128;
    const char* pB1 = (const char*)smB + (wc + 32 + l31) * 128;

    for (int kt = 0; kt < CC; kt += 64) {
#pragma unroll
        for (int j = 0; j < 4; ++j) {
            __builtin_amdgcn_global_load_lds(AS1(Ag + (size_t)j * 32 * CC + kt), AS3(ldsA + j * 4096), 16, 0, 0);
            __builtin_amdgcn_global_load_lds(AS1(Bg + (size_t)j * 32 * CC + kt), AS3(ldsB + j * 4096), 16, 0, 0);
        }
        __syncthreads();
#pragma unroll
        for (int ks = 0; ks < 4; ++ks) {
            const int ck = ((ks * 2 + lh) ^ swz) << 4;   // swizzled chunk byte offset
            bfrag a0 = *(const bfrag*)(pA0 + ck);
            bfrag a1 = *(const bfrag*)(pA1 + ck);
            bfrag b0 = *(const bfrag*)(pB0 + ck);
            bfrag b1 = *(const bfrag*)(pB1 + ck);
            acc00 = __builtin_amdgcn_mfma_f32_32x32x16_bf16(a0, b0, acc00, 0, 0, 0);
            acc01 = __builtin_amdgcn_mfma_f32_32x32x16_bf16(a0, b1, acc01, 0, 0, 0);
            acc10 = __builtin_amdgcn_mfma_f32_32x32x16_bf16(a1, b0, acc10, 0, 0, 0);
            acc11 = __builtin_amdgcn_mfma_f32_32x32x16_bf16(a1, b1, acc11, 0, 0, 0);
        }
        __syncthreads();
    }

    // epilogue: C/D layout (32x32): row = (reg&3) + 8*(reg>>2) + 4*(lane>>5), col = lane&31
    float* outn = out + (size_t)nb * CC * PP;
#pragma unroll
    for (int mi = 0; mi < 2; ++mi) {
        const int obase = m0 + wr + mi * 32;
#pragma unroll
        for (int r = 0; r < 16; ++r) {
            const int rowl = (r & 3) + 8 * (r >> 2) + 4 * lh;
            const int o = obase + rowl;
            const float bias = b3[o];
            float* orow = outn + (size_t)o * PP + p0 + wc + l31;
            float v0 = (mi ? acc10[r] : acc00[r]) + bias;
            float v1 = (mi ? acc11[r] : acc01[r]) + bias;
            orow[0]  = v0 > 0.f ? v0 : 0.f;
            orow[32] = v1 > 0.f ? v1 : 0.f;
        }
    }
}

// ---------------- guarded attention fallback (alpha != 0 only) ----------------
__global__ void fb_e12(const float* __restrict__ x,
                       const float* __restrict__ w1, const float* __restrict__ b1,
                       const float* __restrict__ w2, const float* __restrict__ b2,
                       const float* __restrict__ alpha,
                       float* __restrict__ e1, float* __restrict__ e2) {
    if (alpha[0] == 0.f) return;
    const size_t total = (size_t)NB * DD * PP;
    for (size_t idx = (size_t)blockIdx.x * blockDim.x + threadIdx.x; idx < total;
         idx += (size_t)gridDim.x * blockDim.x) {
        int p = (int)(idx % PP);
        size_t nd = idx / PP;
        int d = (int)(nd % DD);
        int n = (int)(nd / DD);
        const float* xn = x + (size_t)n * CC * PP + p;
        float s1 = b1[d], s2 = b2[d];
        for (int c = 0; c < CC; ++c) {
            float xv = xn[(size_t)c * PP];
            s1 += w1[(size_t)d * CC + c] * xv;
            s2 += w2[(size_t)d * CC + c] * xv;
        }
        e1[idx] = fmaxf(s1, 0.f);
        e2[idx] = fmaxf(s2, 0.f);
    }
}

__global__ void fb_attn(const float* __restrict__ x,
                        const float* __restrict__ e1, const float* __restrict__ e2,
                        const float* __restrict__ alpha,
                        float* __restrict__ out) {
    const float a = alpha[0];
    if (a == 0.f) return;   // uniform early-exit (no barrier crossed)
    __shared__ float s[PP];
    __shared__ float e1i[DD];
    __shared__ float red[256];
    const int t = threadIdx.x;
    for (int ii = blockIdx.x; ii < NB * PP; ii += gridDim.x) {
        const int n = ii >> 12;        // / PP
        const int i = ii & (PP - 1);   // % PP
        const float* e1n = e1 + (size_t)n * DD * PP;
        const float* e2n = e2 + (size_t)n * DD * PP;
        if (t < DD) e1i[t] = e1n[(size_t)t * PP + i];
        __syncthreads();
        for (int j = t; j < PP; j += 256) {
            float acc = 0.f;
            for (int d = 0; d < DD; ++d) acc += e1i[d] * e2n[(size_t)d * PP + j];
            s[j] = acc;
        }
        __syncthreads();
        float m = -INFINITY;
        for (int j = t; j < PP; j += 256) m = fmaxf(m, s[j]);
        red[t] = m; __syncthreads();
        for (int o = 128; o > 0; o >>= 1) { if (t < o) red[t] = fmaxf(red[t], red[t + o]); __syncthreads(); }
        m = red[0]; __syncthreads();
        float l = 0.f;
        for (int j = t; j < PP; j += 256) { float e = __expf(s[j] - m); s[j] = e; l += e; }
        red[t] = l; __syncthreads();
        for (int o = 128; o > 0; o >>= 1) { if (t < o) red[t] += red[t + o]; __syncthreads(); }
        l = red[0]; __syncthreads();
        const float inv = a / l;
        const float* xn = x + (size_t)n * CC * PP;
        float* on = out + (size_t)n * CC * PP;
        for (int c = t; c < CC; c += 256) {
            const float* xr = xn + (size_t)c * PP;
            float acc = 0.f;
            for (int j = 0; j < PP; ++j) acc += s[j] * xr[j];
            on[(size_t)c * PP + i] += inv * acc;
        }
        __syncthreads();
    }
}

extern "C" void kernel_launch(void* const* d_in, const int* in_sizes, int n_in,
                              void* d_out, int out_size, void* d_ws, size_t ws_size,
                              hipStream_t stream) {
    (void)in_sizes; (void)n_in; (void)out_size; (void)ws_size;
    const float* x     = (const float*)d_in[0];
    const float* w1    = (const float*)d_in[1];
    const float* b1    = (const float*)d_in[2];
    const float* w2    = (const float*)d_in[3];
    const float* b2    = (const float*)d_in[4];
    const float* w3    = (const float*)d_in[5];
    const float* b3    = (const float*)d_in[6];
    const float* alpha = (const float*)d_in[7];
    float* out = (float*)d_out;

    // ws: [0,64MB) xT bf16 ; [64MB,72MB) w3b bf16 ; fallback e1/e2 alias [0,32MB)
    unsigned short* xT  = (unsigned short*)d_ws;
    unsigned short* w3b = (unsigned short*)((char*)d_ws + (size_t)NB * PP * CC * 2);
    float* e1 = (float*)d_ws;   // used only on the alpha!=0 path, after gemm consumed xT
    float* e2 = e1 + (size_t)NB * DD * PP;

    cvt_w3<<<dim3(1024), dim3(256), 0, stream>>>(w3, w3b);
    transpose_cvt<<<dim3(PP / 64, CC / 64, NB), dim3(256), 0, stream>>>(x, xT);
    gemm_assembly<<<dim3(PP / 128, CC / 128, NB), dim3(256), 0, stream>>>(w3b, xT, b3, out);
    // attention path: no-ops when alpha == 0 (true for this input set)
    fb_e12<<<dim3(1024), dim3(256), 0, stream>>>(x, w1, b1, w2, b2, alpha, e1, e2);
    fb_attn<<<dim3(2048), dim3(256), 0, stream>>>(x, e1, e2, alpha, out);
}

// Round 3
// 384.215 us; speedup vs baseline: 1.1761x; 1.0143x over previous
//
#include <hip/hip_runtime.h>
#include <math.h>

#define CC 2048   // channels (C)
#define DD 256    // reduced channels (D)
#define PP 4096   // HW = 64*64
#define NB 4      // batch

typedef float f32x16 __attribute__((ext_vector_type(16)));
typedef __bf16 bfrag __attribute__((ext_vector_type(8)));

#define AS1(p) ((const __attribute__((address_space(1))) void*)(p))
#define AS3(p) ((__attribute__((address_space(3))) void*)(p))

__device__ __forceinline__ unsigned short f2bf(float f) {
    unsigned int u = __float_as_uint(f);
    u = (u + 0x7fffu + ((u >> 16) & 1u)) >> 16;
    return (unsigned short)u;
}

// ---------------- w3 fp32 -> bf16 (16 MB read, 8 MB write) ----------------
__global__ __launch_bounds__(256) void cvt_w3(const float* __restrict__ w, unsigned short* __restrict__ o) {
    int base = (blockIdx.x * 256 + threadIdx.x) * 16;   // 1024 blocks * 256 thr * 16 = 4M
#pragma unroll
    for (int j = 0; j < 4; ++j) {
        float4 v = *(const float4*)(w + base + j * 4);
        ushort4 r;
        r.x = f2bf(v.x); r.y = f2bf(v.y); r.z = f2bf(v.z); r.w = f2bf(v.w);
        *(ushort4*)(o + base + j * 4) = r;
    }
}

// ---------------- x [n][c][p] fp32 -> xT [n][p][c] bf16 ----------------
// 64x64 tile; fp32 LDS tile with granule-XOR swizzle (conflict-free both phases):
// tile element (c,p) lives at c*64 + ((p>>2 ^ c>>2)<<2) + (p&3).
__global__ __launch_bounds__(256) void transpose_cvt(const float* __restrict__ x, unsigned short* __restrict__ xT) {
    __shared__ float tile[64 * 64];
    const int n  = blockIdx.z;
    const int c0 = blockIdx.y * 64;
    const int p0 = blockIdx.x * 64;
    const int t  = threadIdx.x;
    const float* xn = x + (size_t)n * CC * PP;
    {
        const int cl = t >> 4;          // 0..15
        const int g  = t & 15;          // granule index = pl>>2
        const int pl = g * 4;
#pragma unroll
        for (int ps = 0; ps < 4; ++ps) {
            const int c = cl + ps * 16;
            float4 v = *(const float4*)(xn + (size_t)(c0 + c) * PP + p0 + pl);
            const int gs = g ^ (c >> 2);
            *(float4*)(tile + c * 64 + gs * 4) = v;
        }
    }
    __syncthreads();
    unsigned short* xTn = xT + (size_t)n * PP * CC;
    {
        const int pl2 = t >> 4;         // 0..15
        const int cq  = t & 15;         // c granule: c4 = cq*4
        const int c4  = cq * 4;
#pragma unroll
        for (int ps = 0; ps < 4; ++ps) {
            const int p  = pl2 + ps * 16;
            const int gs2 = (p >> 2) ^ cq;
            const int base = gs2 * 4 + (p & 3);
            ushort4 r;
            r.x = f2bf(tile[(c4 + 0) * 64 + base]);
            r.y = f2bf(tile[(c4 + 1) * 64 + base]);
            r.z = f2bf(tile[(c4 + 2) * 64 + base]);
            r.w = f2bf(tile[(c4 + 3) * 64 + base]);
            *(ushort4*)(xTn + (size_t)(p0 + p) * CC + c0 + c4) = r;
        }
    }
}

// ---------------- assembly = relu(w3 . x + b3) ----------------
// Block tile 128m x 256p, BK=64. 4 waves (2m x 2p), each computing 64x128 via
// 2x4 of mfma_f32_32x32x16_bf16 -> 0.75 ds_reads per MFMA (was 1.0).
// LDS rows 128B; slot s of row r holds global k-chunk s^(r&7) (XOR applied on
// the GLOBAL address so global_load_lds wave-uniform-base layout is preserved).
__global__ __launch_bounds__(256, 2) void gemm_assembly(
    const unsigned short* __restrict__ w3b,
    const unsigned short* __restrict__ xT,
    const float* __restrict__ b3,
    float* __restrict__ out)
{
    __shared__ __align__(16) unsigned short smA[128 * 64];  // 16KB
    __shared__ __align__(16) unsigned short smB[256 * 64];  // 32KB

    const int t    = threadIdx.x;
    const int wave = t >> 6;
    const int lane = t & 63;
    const int l31  = lane & 31;
    const int lh   = lane >> 5;     // k-half within K=16
    const int swz  = lane & 7;
    const int m0 = blockIdx.y * 128;
    const int p0 = blockIdx.x * 256;
    const int nb = blockIdx.z;

    // staging: thread t covers row rA = t>>3 (+j*32), fetches global chunk g
    const int rA = t >> 3;
    const int g  = (t & 7) ^ (rA & 7);
    const unsigned short* Ag = w3b + (size_t)(m0 + rA) * CC + g * 8;
    const unsigned short* Bg = xT + (size_t)nb * PP * CC + (size_t)(p0 + rA) * CC + g * 8;
    char* ldsA = (char*)smA + wave * 1024;   // + j*4096 per call; HW adds lane*16
    char* ldsB = (char*)smB + wave * 1024;

    const int wr = (wave >> 1) * 64;    // wave m offset (0 or 64)
    const int wc = (wave & 1) * 128;    // wave p offset (0 or 128)

    f32x16 acc[2][4];
#pragma unroll
    for (int mi = 0; mi < 2; ++mi)
#pragma unroll
        for (int ni = 0; ni < 4; ++ni)
            acc[mi][ni] = (f32x16){0.f};

    const char* pA0 = (const char*)smA + (wr + l31) * 128;
    const char* pA1 = (const char*)smA + (wr + 32 + l31) * 128;
    const char* pB0 = (const char*)smB + (wc + l31) * 128;
    const char* pB1 = (const char*)smB + (wc + 32 + l31) * 128;
    const char* pB2 = (const char*)smB + (wc + 64 + l31) * 128;
    const char* pB3 = (const char*)smB + (wc + 96 + l31) * 128;

    for (int kt = 0; kt < CC; kt += 64) {
#pragma unroll
        for (int j = 0; j < 4; ++j)
            __builtin_amdgcn_global_load_lds(AS1(Ag + (size_t)j * 32 * CC + kt), AS3(ldsA + j * 4096), 16, 0, 0);
#pragma unroll
        for (int j = 0; j < 8; ++j)
            __builtin_amdgcn_global_load_lds(AS1(Bg + (size_t)j * 32 * CC + kt), AS3(ldsB + j * 4096), 16, 0, 0);
        __syncthreads();
#pragma unroll
        for (int ks = 0; ks < 4; ++ks) {
            const int ck = ((ks * 2 + lh) ^ swz) << 4;   // swizzled chunk byte offset
            bfrag a0 = *(const bfrag*)(pA0 + ck);
            bfrag a1 = *(const bfrag*)(pA1 + ck);
            bfrag b0 = *(const bfrag*)(pB0 + ck);
            bfrag b1 = *(const bfrag*)(pB1 + ck);
            bfrag b2 = *(const bfrag*)(pB2 + ck);
            bfrag b3v = *(const bfrag*)(pB3 + ck);
            acc[0][0] = __builtin_amdgcn_mfma_f32_32x32x16_bf16(a0, b0,  acc[0][0], 0, 0, 0);
            acc[0][1] = __builtin_amdgcn_mfma_f32_32x32x16_bf16(a0, b1,  acc[0][1], 0, 0, 0);
            acc[0][2] = __builtin_amdgcn_mfma_f32_32x32x16_bf16(a0, b2,  acc[0][2], 0, 0, 0);
            acc[0][3] = __builtin_amdgcn_mfma_f32_32x32x16_bf16(a0, b3v, acc[0][3], 0, 0, 0);
            acc[1][0] = __builtin_amdgcn_mfma_f32_32x32x16_bf16(a1, b0,  acc[1][0], 0, 0, 0);
            acc[1][1] = __builtin_amdgcn_mfma_f32_32x32x16_bf16(a1, b1,  acc[1][1], 0, 0, 0);
            acc[1][2] = __builtin_amdgcn_mfma_f32_32x32x16_bf16(a1, b2,  acc[1][2], 0, 0, 0);
            acc[1][3] = __builtin_amdgcn_mfma_f32_32x32x16_bf16(a1, b3v, acc[1][3], 0, 0, 0);
        }
        __syncthreads();
    }

    // epilogue: C/D layout (32x32): row = (reg&3) + 8*(reg>>2) + 4*(lane>>5), col = lane&31
    float* outn = out + (size_t)nb * CC * PP;
#pragma unroll
    for (int mi = 0; mi < 2; ++mi) {
#pragma unroll
        for (int r = 0; r < 16; ++r) {
            const int rowl = (r & 3) + 8 * (r >> 2) + 4 * lh;
            const int o = m0 + wr + mi * 32 + rowl;
            const float bias = b3[o];
            float* orow = outn + (size_t)o * PP + p0 + wc + l31;
#pragma unroll
            for (int ni = 0; ni < 4; ++ni) {
                float v = acc[mi][ni][r] + bias;
                orow[ni * 32] = v > 0.f ? v : 0.f;
            }
        }
    }
}

// ---------------- guarded attention fallback (alpha != 0 only) ----------------
__global__ void fb_e12(const float* __restrict__ x,
                       const float* __restrict__ w1, const float* __restrict__ b1,
                       const float* __restrict__ w2, const float* __restrict__ b2,
                       const float* __restrict__ alpha,
                       float* __restrict__ e1, float* __restrict__ e2) {
    if (alpha[0] == 0.f) return;
    const size_t total = (size_t)NB * DD * PP;
    for (size_t idx = (size_t)blockIdx.x * blockDim.x + threadIdx.x; idx < total;
         idx += (size_t)gridDim.x * blockDim.x) {
        int p = (int)(idx % PP);
        size_t nd = idx / PP;
        int d = (int)(nd % DD);
        int n = (int)(nd / DD);
        const float* xn = x + (size_t)n * CC * PP + p;
        float s1 = b1[d], s2 = b2[d];
        for (int c = 0; c < CC; ++c) {
            float xv = xn[(size_t)c * PP];
            s1 += w1[(size_t)d * CC + c] * xv;
            s2 += w2[(size_t)d * CC + c] * xv;
        }
        e1[idx] = fmaxf(s1, 0.f);
        e2[idx] = fmaxf(s2, 0.f);
    }
}

__global__ void fb_attn(const float* __restrict__ x,
                        const float* __restrict__ e1, const float* __restrict__ e2,
                        const float* __restrict__ alpha,
                        float* __restrict__ out) {
    const float a = alpha[0];
    if (a == 0.f) return;   // uniform early-exit (no barrier crossed)
    __shared__ float s[PP];
    __shared__ float e1i[DD];
    __shared__ float red[256];
    const int t = threadIdx.x;
    for (int ii = blockIdx.x; ii < NB * PP; ii += gridDim.x) {
        const int n = ii >> 12;        // / PP
        const int i = ii & (PP - 1);   // % PP
        const float* e1n = e1 + (size_t)n * DD * PP;
        const float* e2n = e2 + (size_t)n * DD * PP;
        if (t < DD) e1i[t] = e1n[(size_t)t * PP + i];
        __syncthreads();
        for (int j = t; j < PP; j += 256) {
            float acc = 0.f;
            for (int d = 0; d < DD; ++d) acc += e1i[d] * e2n[(size_t)d * PP + j];
            s[j] = acc;
        }
        __syncthreads();
        float m = -INFINITY;
        for (int j = t; j < PP; j += 256) m = fmaxf(m, s[j]);
        red[t] = m; __syncthreads();
        for (int o = 128; o > 0; o >>= 1) { if (t < o) red[t] = fmaxf(red[t], red[t + o]); __syncthreads(); }
        m = red[0]; __syncthreads();
        float l = 0.f;
        for (int j = t; j < PP; j += 256) { float e = __expf(s[j] - m); s[j] = e; l += e; }
        red[t] = l; __syncthreads();
        for (int o = 128; o > 0; o >>= 1) { if (t < o) red[t] += red[t + o]; __syncthreads(); }
        l = red[0]; __syncthreads();
        const float inv = a / l;
        const float* xn = x + (size_t)n * CC * PP;
        float* on = out + (size_t)n * CC * PP;
        for (int c = t; c < CC; c += 256) {
            const float* xr = xn + (size_t)c * PP;
            float acc = 0.f;
            for (int j = 0; j < PP; ++j) acc += s[j] * xr[j];
            on[(size_t)c * PP + i] += inv * acc;
        }
        __syncthreads();
    }
}

extern "C" void kernel_launch(void* const* d_in, const int* in_sizes, int n_in,
                              void* d_out, int out_size, void* d_ws, size_t ws_size,
                              hipStream_t stream) {
    (void)in_sizes; (void)n_in; (void)out_size; (void)ws_size;
    const float* x     = (const float*)d_in[0];
    const float* w1    = (const float*)d_in[1];
    const float* b1    = (const float*)d_in[2];
    const float* w2    = (const float*)d_in[3];
    const float* b2    = (const float*)d_in[4];
    const float* w3    = (const float*)d_in[5];
    const float* b3    = (const float*)d_in[6];
    const float* alpha = (const float*)d_in[7];
    float* out = (float*)d_out;

    // ws: [0,64MB) xT bf16 ; [64MB,72MB) w3b bf16 ; fallback e1/e2 alias [0,32MB)
    unsigned short* xT  = (unsigned short*)d_ws;
    unsigned short* w3b = (unsigned short*)((char*)d_ws + (size_t)NB * PP * CC * 2);
    float* e1 = (float*)d_ws;   // used only on the alpha!=0 path, after gemm consumed xT
    float* e2 = e1 + (size_t)NB * DD * PP;

    cvt_w3<<<dim3(1024), dim3(256), 0, stream>>>(w3, w3b);
    transpose_cvt<<<dim3(PP / 64, CC / 64, NB), dim3(256), 0, stream>>>(x, xT);
    gemm_assembly<<<dim3(PP / 256, CC / 128, NB), dim3(256), 0, stream>>>(w3b, xT, b3, out);
    // attention path: no-ops when alpha == 0 (true for this input set)
    fb_e12<<<dim3(1024), dim3(256), 0, stream>>>(x, w1, b1, w2, b2, alpha, e1, e2);
    fb_attn<<<dim3(2048), dim3(256), 0, stream>>>(x, e1, e2, alpha, out);
}

// Round 4
// 376.405 us; speedup vs baseline: 1.2005x; 1.0207x over previous
//
#include <hip/hip_runtime.h>
#include <math.h>

#define CC 2048   // channels (C)
#define DD 256    // reduced channels (D)
#define PP 4096   // HW = 64*64
#define NB 4      // batch

typedef float f32x16 __attribute__((ext_vector_type(16)));
typedef __bf16 bfrag __attribute__((ext_vector_type(8)));

#define AS1(p) ((const __attribute__((address_space(1))) void*)(p))
#define AS3(p) ((__attribute__((address_space(3))) void*)(p))

__device__ __forceinline__ unsigned short f2bf(float f) {
    unsigned int u = __float_as_uint(f);
    u = (u + 0x7fffu + ((u >> 16) & 1u)) >> 16;
    return (unsigned short)u;
}

// ---------------- fused: x transpose+cvt (z<NB) and w3 cvt (z==NB) ----------------
// transpose: 64x64 tile; fp32 LDS tile with granule-XOR swizzle (conflict-free).
__global__ __launch_bounds__(256) void prep(const float* __restrict__ x, unsigned short* __restrict__ xT,
                                            const float* __restrict__ w3, unsigned short* __restrict__ w3b) {
    const int t = threadIdx.x;
    if (blockIdx.z == NB) {
        // w3 cvt plane: grid (64,32) covers 2048 blocks; only use those
        int bid = blockIdx.y * 64 + blockIdx.x;   // 0..2047
        int base = (bid * 256 + t) * 8;           // 2048*256*8 = 4M elems
#pragma unroll
        for (int j = 0; j < 2; ++j) {
            float4 v = *(const float4*)(w3 + base + j * 4);
            ushort4 r;
            r.x = f2bf(v.x); r.y = f2bf(v.y); r.z = f2bf(v.z); r.w = f2bf(v.w);
            *(ushort4*)(w3b + base + j * 4) = r;
        }
        return;
    }
    __shared__ float tile[64 * 64];
    const int n  = blockIdx.z;
    const int c0 = blockIdx.y * 64;
    const int p0 = blockIdx.x * 64;
    const float* xn = x + (size_t)n * CC * PP;
    {
        const int cl = t >> 4;          // 0..15
        const int g  = t & 15;          // granule index = pl>>2
        const int pl = g * 4;
#pragma unroll
        for (int ps = 0; ps < 4; ++ps) {
            const int c = cl + ps * 16;
            float4 v = *(const float4*)(xn + (size_t)(c0 + c) * PP + p0 + pl);
            const int gs = g ^ (c >> 2);
            *(float4*)(tile + c * 64 + gs * 4) = v;
        }
    }
    __syncthreads();
    unsigned short* xTn = xT + (size_t)n * PP * CC;
    {
        const int pl2 = t >> 4;         // 0..15
        const int cq  = t & 15;         // c granule: c4 = cq*4
        const int c4  = cq * 4;
#pragma unroll
        for (int ps = 0; ps < 4; ++ps) {
            const int p  = pl2 + ps * 16;
            const int gs2 = (p >> 2) ^ cq;
            const int base = gs2 * 4 + (p & 3);
            ushort4 r;
            r.x = f2bf(tile[(c4 + 0) * 64 + base]);
            r.y = f2bf(tile[(c4 + 1) * 64 + base]);
            r.z = f2bf(tile[(c4 + 2) * 64 + base]);
            r.w = f2bf(tile[(c4 + 3) * 64 + base]);
            *(ushort4*)(xTn + (size_t)(p0 + p) * CC + c0 + c4) = r;
        }
    }
}

// ---------------- assembly = relu(w3 . x + b3) ----------------
// Block tile 128m x 256p, BK=64, 512 threads = 8 waves (2m x 4p), each wave
// 64x64 via 2x2 of mfma_f32_32x32x16_bf16. Occupancy-first config: acc=64
// AGPR/wave -> 4 waves/SIMD, 2 blocks/CU co-resident (LDS 48KB x 2).
// LDS rows 128B; slot s of row r holds global k-chunk s^(r&7) (XOR applied on
// the GLOBAL address so global_load_lds wave-uniform-base layout is preserved).
__global__ __launch_bounds__(512, 4) void gemm_assembly(
    const unsigned short* __restrict__ w3b,
    const unsigned short* __restrict__ xT,
    const float* __restrict__ b3,
    float* __restrict__ out)
{
    __shared__ __align__(16) unsigned short smA[128 * 64];  // 16KB
    __shared__ __align__(16) unsigned short smB[256 * 64];  // 32KB

    const int t    = threadIdx.x;
    const int wave = t >> 6;
    const int lane = t & 63;
    const int l31  = lane & 31;
    const int lh   = lane >> 5;     // k-half within K=16
    const int swz  = lane & 7;
    const int m0 = blockIdx.y * 128;
    const int p0 = blockIdx.x * 256;
    const int nb = blockIdx.z;

    // staging: thread t covers row rA = t>>3 (+j*64), fetches global chunk g
    const int rA = t >> 3;          // 0..63
    const int g  = (t & 7) ^ (rA & 7);
    const unsigned short* Ag = w3b + (size_t)(m0 + rA) * CC + g * 8;
    const unsigned short* Bg = xT + (size_t)nb * PP * CC + (size_t)(p0 + rA) * CC + g * 8;
    char* ldsA = (char*)smA + wave * 1024;   // + j*8192 per issue; HW adds lane*16
    char* ldsB = (char*)smB + wave * 1024;

    const int wr = (wave >> 2) * 64;    // wave m offset (0 or 64)
    const int wc = (wave & 3) * 64;     // wave p offset (0/64/128/192)

    f32x16 acc00 = {}, acc01 = {}, acc10 = {}, acc11 = {};

    const char* pA0 = (const char*)smA + (wr + l31) * 128;
    const char* pA1 = (const char*)smA + (wr + 32 + l31) * 128;
    const char* pB0 = (const char*)smB + (wc + l31) * 128;
    const char* pB1 = (const char*)smB + (wc + 32 + l31) * 128;

    for (int kt = 0; kt < CC; kt += 64) {
#pragma unroll
        for (int j = 0; j < 2; ++j)
            __builtin_amdgcn_global_load_lds(AS1(Ag + (size_t)j * 64 * CC + kt), AS3(ldsA + j * 8192), 16, 0, 0);
#pragma unroll
        for (int j = 0; j < 4; ++j)
            __builtin_amdgcn_global_load_lds(AS1(Bg + (size_t)j * 64 * CC + kt), AS3(ldsB + j * 8192), 16, 0, 0);
        __syncthreads();
#pragma unroll
        for (int ks = 0; ks < 4; ++ks) {
            const int ck = ((ks * 2 + lh) ^ swz) << 4;   // swizzled chunk byte offset
            bfrag a0 = *(const bfrag*)(pA0 + ck);
            bfrag a1 = *(const bfrag*)(pA1 + ck);
            bfrag b0 = *(const bfrag*)(pB0 + ck);
            bfrag b1 = *(const bfrag*)(pB1 + ck);
            acc00 = __builtin_amdgcn_mfma_f32_32x32x16_bf16(a0, b0, acc00, 0, 0, 0);
            acc01 = __builtin_amdgcn_mfma_f32_32x32x16_bf16(a0, b1, acc01, 0, 0, 0);
            acc10 = __builtin_amdgcn_mfma_f32_32x32x16_bf16(a1, b0, acc10, 0, 0, 0);
            acc11 = __builtin_amdgcn_mfma_f32_32x32x16_bf16(a1, b1, acc11, 0, 0, 0);
        }
        __syncthreads();
    }

    // epilogue: C/D layout (32x32): row = (reg&3) + 8*(reg>>2) + 4*(lane>>5), col = lane&31
    float* outn = out + (size_t)nb * CC * PP;
#pragma unroll
    for (int mi = 0; mi < 2; ++mi) {
#pragma unroll
        for (int r = 0; r < 16; ++r) {
            const int rowl = (r & 3) + 8 * (r >> 2) + 4 * lh;
            const int o = m0 + wr + mi * 32 + rowl;
            const float bias = b3[o];
            float* orow = outn + (size_t)o * PP + p0 + wc + l31;
            float v0 = (mi ? acc10[r] : acc00[r]) + bias;
            float v1 = (mi ? acc11[r] : acc01[r]) + bias;
            orow[0]  = v0 > 0.f ? v0 : 0.f;
            orow[32] = v1 > 0.f ? v1 : 0.f;
        }
    }
}

// ---------------- guarded attention fallback (alpha != 0 only) ----------------
__global__ void fb_e12(const float* __restrict__ x,
                       const float* __restrict__ w1, const float* __restrict__ b1,
                       const float* __restrict__ w2, const float* __restrict__ b2,
                       const float* __restrict__ alpha,
                       float* __restrict__ e1, float* __restrict__ e2) {
    if (alpha[0] == 0.f) return;
    const size_t total = (size_t)NB * DD * PP;
    for (size_t idx = (size_t)blockIdx.x * blockDim.x + threadIdx.x; idx < total;
         idx += (size_t)gridDim.x * blockDim.x) {
        int p = (int)(idx % PP);
        size_t nd = idx / PP;
        int d = (int)(nd % DD);
        int n = (int)(nd / DD);
        const float* xn = x + (size_t)n * CC * PP + p;
        float s1 = b1[d], s2 = b2[d];
        for (int c = 0; c < CC; ++c) {
            float xv = xn[(size_t)c * PP];
            s1 += w1[(size_t)d * CC + c] * xv;
            s2 += w2[(size_t)d * CC + c] * xv;
        }
        e1[idx] = fmaxf(s1, 0.f);
        e2[idx] = fmaxf(s2, 0.f);
    }
}

__global__ void fb_attn(const float* __restrict__ x,
                        const float* __restrict__ e1, const float* __restrict__ e2,
                        const float* __restrict__ alpha,
                        float* __restrict__ out) {
    const float a = alpha[0];
    if (a == 0.f) return;   // uniform early-exit (no barrier crossed)
    __shared__ float s[PP];
    __shared__ float e1i[DD];
    __shared__ float red[256];
    const int t = threadIdx.x;
    for (int ii = blockIdx.x; ii < NB * PP; ii += gridDim.x) {
        const int n = ii >> 12;        // / PP
        const int i = ii & (PP - 1);   // % PP
        const float* e1n = e1 + (size_t)n * DD * PP;
        const float* e2n = e2 + (size_t)n * DD * PP;
        if (t < DD) e1i[t] = e1n[(size_t)t * PP + i];
        __syncthreads();
        for (int j = t; j < PP; j += 256) {
            float acc = 0.f;
            for (int d = 0; d < DD; ++d) acc += e1i[d] * e2n[(size_t)d * PP + j];
            s[j] = acc;
        }
        __syncthreads();
        float m = -INFINITY;
        for (int j = t; j < PP; j += 256) m = fmaxf(m, s[j]);
        red[t] = m; __syncthreads();
        for (int o = 128; o > 0; o >>= 1) { if (t < o) red[t] = fmaxf(red[t], red[t + o]); __syncthreads(); }
        m = red[0]; __syncthreads();
        float l = 0.f;
        for (int j = t; j < PP; j += 256) { float e = __expf(s[j] - m); s[j] = e; l += e; }
        red[t] = l; __syncthreads();
        for (int o = 128; o > 0; o >>= 1) { if (t < o) red[t] += red[t + o]; __syncthreads(); }
        l = red[0]; __syncthreads();
        const float inv = a / l;
        const float* xn = x + (size_t)n * CC * PP;
        float* on = out + (size_t)n * CC * PP;
        for (int c = t; c < CC; c += 256) {
            const float* xr = xn + (size_t)c * PP;
            float acc = 0.f;
            for (int j = 0; j < PP; ++j) acc += s[j] * xr[j];
            on[(size_t)c * PP + i] += inv * acc;
        }
        __syncthreads();
    }
}

extern "C" void kernel_launch(void* const* d_in, const int* in_sizes, int n_in,
                              void* d_out, int out_size, void* d_ws, size_t ws_size,
                              hipStream_t stream) {
    (void)in_sizes; (void)n_in; (void)out_size; (void)ws_size;
    const float* x     = (const float*)d_in[0];
    const float* w1    = (const float*)d_in[1];
    const float* b1    = (const float*)d_in[2];
    const float* w2    = (const float*)d_in[3];
    const float* b2    = (const float*)d_in[4];
    const float* w3    = (const float*)d_in[5];
    const float* b3    = (const float*)d_in[6];
    const float* alpha = (const float*)d_in[7];
    float* out = (float*)d_out;

    // ws: [0,64MB) xT bf16 ; [64MB,72MB) w3b bf16 ; fallback e1/e2 alias [0,32MB)
    unsigned short* xT  = (unsigned short*)d_ws;
    unsigned short* w3b = (unsigned short*)((char*)d_ws + (size_t)NB * PP * CC * 2);
    float* e1 = (float*)d_ws;   // used only on the alpha!=0 path, after gemm consumed xT
    float* e2 = e1 + (size_t)NB * DD * PP;

    // z<NB: transpose+cvt of x; z==NB: w3 cvt (saves one launch)
    prep<<<dim3(PP / 64, CC / 64, NB + 1), dim3(256), 0, stream>>>(x, xT, w3, w3b);
    gemm_assembly<<<dim3(PP / 256, CC / 128, NB), dim3(512), 0, stream>>>(w3b, xT, b3, out);
    // attention path: no-ops when alpha == 0 (true for this input set)
    fb_e12<<<dim3(512), dim3(256), 0, stream>>>(x, w1, b1, w2, b2, alpha, e1, e2);
    fb_attn<<<dim3(1024), dim3(256), 0, stream>>>(x, e1, e2, alpha, out);
}